// Round 6
// baseline (1036.264 us; speedup 1.0000x reference)
//
#include <hip/hip_runtime.h>
#include <cstdint>

#define D 128
#define K 1024
#define NB 4096
#define BB 8     // rows per block in mode/loss kernel
#define TK 64    // centroid rows per LDS tile (fallback path)
#define FEPS 1e-6f

typedef unsigned long long u64;
typedef unsigned int u32;
typedef unsigned short u16;

// ============================================================================
// ws layout (fast path):
//   sval : [D][K] f32   — each column of centroids sorted ascending   (512KB)
//   shead: [D][K] u16   — run-head original index per sorted position (256KB)
//   iminT: [D][NB] u16  — per-(d,b) argmin centroid index, d-major    (1MB)
//   ext  : [0:128) col min val, [128:256) col max val (f32);
//          as ints [256:384) first idx of min, [384:512) first idx of max (2KB)
// ============================================================================

// ---------------------------------------------------------------------------
// Prep kernel: per-column BUCKET sort by (value, index) + run heads + extremes.
// One block (256 thr) per column. O(n) passes, no O(log^2) serial network —
// the register bitonic was latency-bound at 1 wave/CU (43.6us, VALUBusy 3.3%).
// ---------------------------------------------------------------------------
__global__ __launch_bounds__(256) void prep_columns_kernel(
    const float* __restrict__ cen, float* __restrict__ sval,
    u16* __restrict__ shead, float* __restrict__ ext, float* __restrict__ out)
{
    __shared__ u64 keys[K];                       // 8 KB sorted (value,idx)
    __shared__ u32 hist[256], tmp[256], cursor[256];
    __shared__ u32 redA[4], redB[4];

    const int dcol = blockIdx.x;
    const int t = threadIdx.x;
    if (dcol == 0 && t == 0) out[0] = 0.0f;       // replaces memset dispatch

    // load 4 elems (column gather), monotone map f32 -> u32
    u32 um[4]; int ki[4];
    #pragma unroll
    for (int j = 0; j < 4; ++j) {
        int k = j * 256 + t;
        ki[j] = k;
        float v = cen[k * D + dcol];
        u32 u = __float_as_uint(v);
        um[j] = (u & 0x80000000u) ? ~u : (u | 0x80000000u);
    }
    // min/max reduce (wave shfl + LDS combine)
    u32 mn = um[0], mx = um[0];
    #pragma unroll
    for (int j = 1; j < 4; ++j) { mn = min(mn, um[j]); mx = max(mx, um[j]); }
    #pragma unroll
    for (int s = 32; s >= 1; s >>= 1) {
        mn = min(mn, (u32)__shfl_xor((int)mn, s, 64));
        mx = max(mx, (u32)__shfl_xor((int)mx, s, 64));
    }
    if ((t & 63) == 0) { redA[t >> 6] = mn; redB[t >> 6] = mx; }
    hist[t] = 0u;
    __syncthreads();
    const u32 umin = min(min(redA[0], redA[1]), min(redA[2], redA[3]));
    const u32 umax = max(max(redB[0], redB[1]), max(redB[2], redB[3]));
    const u64 range1 = (u64)(umax - umin) + 1;

    // histogram over 256 equal-width buckets of the mapped range
    int bk[4];
    #pragma unroll
    for (int j = 0; j < 4; ++j) {
        bk[j] = (int)(((u64)(um[j] - umin) << 8) / range1);   // 0..255, monotone
        atomicAdd(&hist[bk[j]], 1u);
    }
    __syncthreads();
    // inclusive prefix in tmp (Hillis-Steele)
    tmp[t] = hist[t];
    __syncthreads();
    for (int s = 1; s < 256; s <<= 1) {
        u32 v = (t >= s) ? tmp[t - s] : 0u;
        __syncthreads();
        tmp[t] += v;
        __syncthreads();
    }
    cursor[t] = tmp[t] - hist[t];                 // exclusive start
    __syncthreads();
    // scatter into bucket-major slots (within-bucket order arbitrary here)
    #pragma unroll
    for (int j = 0; j < 4; ++j) {
        u32 slot = atomicAdd(&cursor[bk[j]], 1u);
        keys[slot] = ((u64)um[j] << 32) | (u32)ki[j];
    }
    __syncthreads();
    // per-bucket insertion sort by full (value,idx) key: thread t owns bucket t
    {
        const int beg = (int)(tmp[t] - hist[t]);
        const int end = (int)tmp[t];
        for (int i = beg + 1; i < end; ++i) {
            u64 kv = keys[i];
            int p = i - 1;
            while (p >= beg && keys[p] > kv) { keys[p + 1] = keys[p]; --p; }
            keys[p + 1] = kv;
        }
    }
    __syncthreads();
    // run heads + outputs (identical semantics to verified bitonic path)
    #pragma unroll
    for (int j = 0; j < 4; ++j) {
        int p = j * 256 + t;
        u64 kp = keys[p];
        u32 vb = (u32)(kp >> 32);
        int p0 = p;
        while (p0 > 0 && (u32)(keys[p0 - 1] >> 32) == vb) --p0;   // rare (ties)
        int head = (int)(keys[p0] & 1023u);
        u32 u = (vb & 0x80000000u) ? (vb & 0x7FFFFFFFu) : ~vb;    // unmap
        float v = __uint_as_float(u);
        sval[dcol * K + p] = v;
        shead[dcol * K + p] = (u16)head;
        if (p == 0)     { ext[dcol]     = v; ((int*)ext)[2 * D + dcol] = head; }
        if (p == K - 1) { ext[D + dcol] = v; ((int*)ext)[3 * D + dcol] = head; }
    }
}

// ---------------------------------------------------------------------------
// Kernel A: argmin search with the column LDS-RESIDENT (no divergent global
// gathers — round-5's main-kernel tax). Block = (column, 1024-row chunk);
// 4 independent search chains per thread hide LDS latency.
// ---------------------------------------------------------------------------
__global__ __launch_bounds__(256) void search_kernel(
    const float* __restrict__ x, const float* __restrict__ sval,
    const u16* __restrict__ shead, u16* __restrict__ iminT)
{
    __shared__ float svs[K];   // 4 KB sorted column values
    __shared__ u16 shs[K];     // 2 KB run-head indices

    const int col = blockIdx.x & (D - 1);
    const int chunk = blockIdx.x >> 7;
    const int t = threadIdx.x;

    ((float4*)svs)[t] = ((const float4*)(sval + col * K))[t];
    ((uint2*)shs)[t]  = ((const uint2*)(shead + col * K))[t];
    __syncthreads();

    const int b0 = chunk * 1024;
    float xq[4];
    #pragma unroll
    for (int j = 0; j < 4; ++j)
        xq[j] = x[(size_t)(b0 + j * 256 + t) * D + col];   // per-lane gather, once

    // branchless binary search in LDS: pos = last index with sval <= x
    int pos[4];
    #pragma unroll
    for (int r = 0; r < 4; ++r) pos[r] = -1;
    #pragma unroll
    for (int s = K; s >= 1; s >>= 1) {
        #pragma unroll
        for (int r = 0; r < 4; ++r) {
            int cand = pos[r] + s;
            int cc = cand > K - 1 ? K - 1 : cand;
            float v = svs[cc];
            if (cand <= K - 1 && v <= xq[r]) pos[r] = cand;
        }
    }
    #pragma unroll
    for (int r = 0; r < 4; ++r) {
        int p1 = pos[r], p2 = pos[r] + 1;
        int c1 = p1 < 0 ? 0 : p1;
        int c2 = p2 > K - 1 ? K - 1 : p2;
        float v1 = svs[c1], v2 = svs[c2];
        int h1 = shs[c1], h2 = shs[c2];
        float d1 = xq[r] - v1, d2 = xq[r] - v2;
        float s1 = d1 * d1, s2 = d2 * d2;
        if (p1 < 0) s1 = 3.4e38f;
        if (p2 > K - 1) s2 = 3.4e38f;
        int idx;
        if (s1 < s2) idx = h1;
        else if (s2 < s1) idx = h2;
        else idx = h1 < h2 ? h1 : h2;       // sq tie -> smaller original index
        iminT[(size_t)col * NB + b0 + r * 256 + t] = (u16)idx;   // coalesced
    }
}

// ---------------------------------------------------------------------------
// Kernel B: mode (byte-packed LDS counts) + extremes argmax + triplet loss.
// Search machinery replaced by reading iminT. Counting/scan/loss logic is the
// round-5-verified v3 code.
// ---------------------------------------------------------------------------
__global__ __launch_bounds__(256) void mode_loss_kernel(
    const float* __restrict__ x, const float* __restrict__ cen,
    const u16* __restrict__ iminT, const float* __restrict__ ext,
    float* __restrict__ out)
{
    __shared__ float xs[BB * D];                // 4 KB
    __shared__ u32 cntA[BB * K / 4];            // 8 KB byte-packed (idx_min)
    __shared__ u32 cntB[BB * K / 4];            // 8 KB byte-packed (idx_max)
    __shared__ int modes[2 * BB];

    const int t = threadIdx.x;
    const int b0 = blockIdx.x * BB;

    ((float4*)xs)[t] = ((const float4*)(x + (size_t)b0 * D))[t];
    {
        uint4 z = make_uint4(0u, 0u, 0u, 0u);
        uint4* a4 = (uint4*)cntA;
        uint4* b4 = (uint4*)cntB;
        #pragma unroll
        for (int j = 0; j < 2; ++j) { a4[t + 256 * j] = z; b4[t + 256 * j] = z; }
    }
    __syncthreads();

    // idx_min counts from iminT: thread t covers dim dd, rows half*4..half*4+3
    {
        const int dd = t >> 1, half = t & 1;
        uint2 w = *(const uint2*)(iminT + (size_t)dd * NB + b0 + half * 4);
        int i0 = (int)(w.x & 0xFFFFu), i1 = (int)(w.x >> 16);
        int i2 = (int)(w.y & 0xFFFFu), i3 = (int)(w.y >> 16);
        const int rr = half * 4;
        atomicAdd(&cntA[((rr + 0) << 8) + (i0 >> 2)], 1u << ((i0 & 3) * 8));
        atomicAdd(&cntA[((rr + 1) << 8) + (i1 >> 2)], 1u << ((i1 & 3) * 8));
        atomicAdd(&cntA[((rr + 2) << 8) + (i2 >> 2)], 1u << ((i2 & 3) * 8));
        atomicAdd(&cntA[((rr + 3) << 8) + (i3 >> 2)], 1u << ((i3 & 3) * 8));
    }

    // idx_max from column extremes (reference rounding), direct count-atomic
    const int d = t & (D - 1);
    const int g = t >> 7;
    {
        float cminv = ext[d], cmaxv = ext[D + d];
        int cmini = ((const int*)ext)[2 * D + d];
        int cmaxi = ((const int*)ext)[3 * D + d];
        #pragma unroll
        for (int r = 0; r < 4; ++r) {
            float xv = xs[(g * 4 + r) * D + d];
            float d1 = xv - cminv;
            float d2 = xv - cmaxv;
            float s1 = d1 * d1, s2 = d2 * d2;
            int idx;
            if (s1 > s2) idx = cmini;
            else if (s2 > s1) idx = cmaxi;
            else idx = (cmini < cmaxi) ? cmini : cmaxi;
            const int rr = g * 4 + r;
            atomicAdd(&cntB[(rr << 8) + (idx >> 2)], 1u << ((idx & 3) * 8));
        }
    }
    __syncthreads();

    // mode scan: 32 lanes per row, 8 packed words each, both buffers at once
    const int row = t >> 5;
    const int lane = t & 31;
    {
        u32 bkeyA = 0u, bkeyB = 0u;
        #pragma unroll
        for (int j = 0; j < 8; ++j) {
            const int w = j * 32 + lane;
            u32 wA = cntA[(row << 8) + w];
            u32 wB = cntB[(row << 8) + w];
            #pragma unroll
            for (int sub = 0; sub < 4; ++sub) {
                const u32 idx = (u32)(w * 4 + sub);
                u32 cA = (wA >> (sub * 8)) & 0xFFu;
                u32 cB = (wB >> (sub * 8)) & 0xFFu;
                u32 kA = (cA << 10) | (1023u - idx);
                u32 kB = (cB << 10) | (1023u - idx);
                bkeyA = kA > bkeyA ? kA : bkeyA;
                bkeyB = kB > bkeyB ? kB : bkeyB;
            }
        }
        #pragma unroll
        for (int m = 16; m >= 1; m >>= 1) {
            u32 oA = __shfl_xor(bkeyA, m);
            u32 oB = __shfl_xor(bkeyB, m);
            bkeyA = oA > bkeyA ? oA : bkeyA;
            bkeyB = oB > bkeyB ? oB : bkeyB;
        }
        if (lane == 0) {
            modes[row]      = 1023 - (int)(bkeyA & 1023u);
            modes[BB + row] = 1023 - (int)(bkeyB & 1023u);
        }
    }
    __syncthreads();

    // triplet distances: 32 lanes per row, 4 dims each
    {
        int pm = modes[row];
        int nm = modes[BB + row];
        const float* pr = cen + (size_t)pm * D;
        const float* nr = cen + (size_t)nm * D;
        float a1 = 0.f, a2 = 0.f, a3 = 0.f;
        #pragma unroll
        for (int j = 0; j < 4; ++j) {
            int dd = j * 32 + lane;
            float xv = xs[row * D + dd];
            float pv = pr[dd], nv = nr[dd];
            float e1 = xv - pv + FEPS;
            float e2 = xv - nv + FEPS;
            float e3 = pv - nv + FEPS;
            a1 += e1 * e1; a2 += e2 * e2; a3 += e3 * e3;
        }
        #pragma unroll
        for (int m = 16; m >= 1; m >>= 1) {
            a1 += __shfl_xor(a1, m);
            a2 += __shfl_xor(a2, m);
            a3 += __shfl_xor(a3, m);
        }
        if (lane == 0) {
            float dp = sqrtf(a1);
            float dneg = fminf(sqrtf(a2), sqrtf(a3));
            float term = dp - dneg + 1.0f;
            if (term > 0.f) atomicAdd(out, term * (1.0f / NB));
        }
    }
}

// ===========================================================================
// Fallback path (verified round-1 kernels) for small ws_size
// ===========================================================================
__global__ __launch_bounds__(256) void col_extremes_kernel(
    const float* __restrict__ cen, float* __restrict__ ws)
{
    __shared__ float mv[256]; __shared__ int mi[256];
    __shared__ float Mv[256]; __shared__ int Mi[256];
    const int dcol = blockIdx.x;
    const int t = threadIdx.x;

    float lminv = 3.4e38f; int lmini = 0;
    float lmaxv = -3.4e38f; int lmaxi = 0;
    #pragma unroll
    for (int j = 0; j < 4; ++j) {
        int k = t * 4 + j;
        float v = cen[k * D + dcol];
        if (v < lminv) { lminv = v; lmini = k; }
        if (v > lmaxv) { lmaxv = v; lmaxi = k; }
    }
    mv[t] = lminv; mi[t] = lmini; Mv[t] = lmaxv; Mi[t] = lmaxi;
    __syncthreads();
    for (int s = 128; s > 0; s >>= 1) {
        if (t < s) {
            float ov = mv[t + s]; int oi = mi[t + s];
            if (ov < mv[t] || (ov == mv[t] && oi < mi[t])) { mv[t] = ov; mi[t] = oi; }
            float Ov = Mv[t + s]; int Oi = Mi[t + s];
            if (Ov > Mv[t] || (Ov == Mv[t] && Oi < Mi[t])) { Mv[t] = Ov; Mi[t] = Oi; }
        }
        __syncthreads();
    }
    if (t == 0) {
        ws[dcol]     = mv[0];
        ws[D + dcol] = Mv[0];
        ((int*)ws)[2 * D + dcol] = mi[0];
        ((int*)ws)[3 * D + dcol] = Mi[0];
    }
}

__global__ __launch_bounds__(256) void cluster_triplet_kernel(
    const float* __restrict__ x, const float* __restrict__ cen,
    const float* __restrict__ ws, float* __restrict__ out)
{
    __shared__ float ctile[TK * D];
    __shared__ float xs[BB * D];
    __shared__ u16 imin[BB * D];
    __shared__ u16 imax[BB * D];
    __shared__ int modes[2 * BB];

    const int t = threadIdx.x;
    const int b0 = blockIdx.x * BB;

    ((float4*)xs)[t] = ((const float4*)(x + (size_t)b0 * D))[t];
    __syncthreads();

    const int d = t & (D - 1);
    const int g = t >> 7;

    float xr[4];
    #pragma unroll
    for (int r = 0; r < 4; ++r) xr[r] = xs[(g * 4 + r) * D + d];

    float best[4]; int bidx[4];
    #pragma unroll
    for (int r = 0; r < 4; ++r) { best[r] = 3.4e38f; bidx[r] = 0; }

    for (int kt = 0; kt < K / TK; ++kt) {
        __syncthreads();
        {
            const float4* src = (const float4*)(cen + (size_t)kt * TK * D);
            float4* dst = (float4*)ctile;
            #pragma unroll
            for (int j = 0; j < 8; ++j) dst[t + 256 * j] = src[t + 256 * j];
        }
        __syncthreads();
        #pragma unroll 8
        for (int kk = 0; kk < TK; ++kk) {
            float cv = ctile[kk * D + d];
            int kg = kt * TK + kk;
            #pragma unroll
            for (int r = 0; r < 4; ++r) {
                float ad = fabsf(xr[r] - cv);
                if (ad < best[r]) { best[r] = ad; bidx[r] = kg; }
            }
        }
    }

    #pragma unroll
    for (int r = 0; r < 4; ++r) imin[(g * 4 + r) * D + d] = (u16)bidx[r];

    {
        float cminv = ws[d], cmaxv = ws[D + d];
        int cmini = ((const int*)ws)[2 * D + d];
        int cmaxi = ((const int*)ws)[3 * D + d];
        #pragma unroll
        for (int r = 0; r < 4; ++r) {
            float d1 = xr[r] - cminv;
            float d2 = xr[r] - cmaxv;
            float s1 = d1 * d1, s2 = d2 * d2;
            int idx;
            if (s1 > s2) idx = cmini;
            else if (s2 > s1) idx = cmaxi;
            else idx = (cmini < cmaxi) ? cmini : cmaxi;
            imax[(g * 4 + r) * D + d] = (u16)idx;
        }
    }
    __syncthreads();

    u32* counts = (u32*)ctile;
    const int row = t >> 5;
    const int lane = t & 31;
    for (int pass = 0; pass < 2; ++pass) {
        {
            uint4* cz = (uint4*)counts;
            uint4 z = make_uint4(0u, 0u, 0u, 0u);
            #pragma unroll
            for (int j = 0; j < 8; ++j) cz[t + 256 * j] = z;
        }
        __syncthreads();
        const u16* src = (pass == 0) ? imin : imax;
        #pragma unroll
        for (int r = 0; r < 4; ++r) {
            int rr = g * 4 + r;
            atomicAdd(&counts[rr * K + (int)src[rr * D + d]], 1u);
        }
        __syncthreads();
        u32 bkey = 0u;
        for (int j = 0; j < 32; ++j) {
            int idx = j * 32 + lane;
            u32 cnt = counts[row * K + idx];
            u32 key = (cnt << 10) | (1023u - (u32)idx);
            bkey = (key > bkey) ? key : bkey;
        }
        #pragma unroll
        for (int m = 16; m >= 1; m >>= 1) {
            u32 o = __shfl_xor(bkey, m);
            bkey = (o > bkey) ? o : bkey;
        }
        if (lane == 0) modes[pass * BB + row] = 1023 - (int)(bkey & 1023u);
        __syncthreads();
    }

    {
        int pm = modes[0 * BB + row];
        int nm = modes[1 * BB + row];
        const float* pr = cen + (size_t)pm * D;
        const float* nr = cen + (size_t)nm * D;
        float a1 = 0.f, a2 = 0.f, a3 = 0.f;
        #pragma unroll
        for (int j = 0; j < 4; ++j) {
            int dd = j * 32 + lane;
            float xv = xs[row * D + dd];
            float pv = pr[dd], nv = nr[dd];
            float e1 = xv - pv + FEPS;
            float e2 = xv - nv + FEPS;
            float e3 = pv - nv + FEPS;
            a1 += e1 * e1; a2 += e2 * e2; a3 += e3 * e3;
        }
        #pragma unroll
        for (int m = 16; m >= 1; m >>= 1) {
            a1 += __shfl_xor(a1, m);
            a2 += __shfl_xor(a2, m);
            a3 += __shfl_xor(a3, m);
        }
        if (lane == 0) {
            float dp = sqrtf(a1);
            float dneg = fminf(sqrtf(a2), sqrtf(a3));
            float term = dp - dneg + 1.0f;
            if (term > 0.f) atomicAdd(out, term * (1.0f / NB));
        }
    }
}

extern "C" void kernel_launch(void* const* d_in, const int* in_sizes, int n_in,
                              void* d_out, int out_size, void* d_ws, size_t ws_size,
                              hipStream_t stream) {
    (void)in_sizes; (void)n_in; (void)out_size;
    const float* x   = (const float*)d_in[0];   // [4096,128] f32
    const float* cen = (const float*)d_in[1];   // [1024,128] f32
    float* out = (float*)d_out;                 // scalar f32

    const size_t need = (size_t)D * K * 4        // sval
                      + (size_t)D * K * 2        // shead
                      + (size_t)D * NB * 2       // iminT
                      + (size_t)4 * D * 4;       // ext
    if (ws_size >= need) {
        float* sval = (float*)d_ws;                                 // 512 KB
        u16* shead  = (u16*)(sval + D * K);                         // 256 KB
        u16* iminT  = shead + D * K;                                // 1 MB
        float* ext  = (float*)(iminT + (size_t)D * NB);             // 2 KB
        prep_columns_kernel<<<D, 256, 0, stream>>>(cen, sval, shead, ext, out);
        search_kernel<<<D * (NB / 1024), 256, 0, stream>>>(x, sval, shead, iminT);
        mode_loss_kernel<<<NB / BB, 256, 0, stream>>>(x, cen, iminT, ext, out);
    } else {
        float* ws = (float*)d_ws;
        hipMemsetAsync(d_out, 0, sizeof(float), stream);
        col_extremes_kernel<<<D, 256, 0, stream>>>(cen, ws);
        cluster_triplet_kernel<<<NB / BB, 256, 0, stream>>>(x, cen, ws, out);
    }
}

// Round 7
// 116.918 us; speedup vs baseline: 8.8632x; 8.8632x over previous
//
#include <hip/hip_runtime.h>
#include <cstdint>

#define D 128
#define K 1024
#define NB 4096
#define BB 8     // rows per block in mode/loss kernel
#define TK 64    // centroid rows per LDS tile (fallback path)
#define FEPS 1e-6f

typedef unsigned long long u64;
typedef unsigned int u32;
typedef unsigned short u16;

// ============================================================================
// ws layout (fast path):
//   sval : [D][K] f32   — each column of centroids sorted ascending   (512KB)
//   shead: [D][K] u16   — run-head original index per sorted position (256KB)
//   iminT: [D][NB] u16  — per-(d,b) argmin centroid index, d-major    (1MB)
//   ext  : [0:128) col min val, [128:256) col max val (f32);
//          as ints [256:384) first idx of min, [384:512) first idx of max (2KB)
// ============================================================================

// ---------------------------------------------------------------------------
// Prep kernel: per-column RANK sort by (value, index) + run heads + extremes.
// One block (256 thr) per column. Rank = count of smaller keys — O(K^2/P),
// fully data-parallel, distribution-immune (round 6's bucket sort degenerated
// catastrophically on IEEE-bit-space skew: 976us, one thread sorting a
// ~300-element bucket serially). Scan reads are lane-uniform -> LDS broadcast.
// ---------------------------------------------------------------------------
__global__ __launch_bounds__(256) void prep_columns_kernel(
    const float* __restrict__ cen, float* __restrict__ sval,
    u16* __restrict__ shead, float* __restrict__ ext, float* __restrict__ out)
{
    __shared__ u64 keys[K];    // 8 KB original-order keys
    __shared__ u64 skeys[K];   // 8 KB sorted keys

    const int dcol = blockIdx.x;
    const int t = threadIdx.x;
    if (dcol == 0 && t == 0) out[0] = 0.0f;       // replaces memset dispatch

    // load 4 elems (column gather), monotone map f32 -> u32, key=(val<<32)|idx
    u64 my[4];
    #pragma unroll
    for (int j = 0; j < 4; ++j) {
        int k = j * 256 + t;
        float v = cen[k * D + dcol];
        u32 u = __float_as_uint(v);
        u = (u & 0x80000000u) ? ~u : (u | 0x80000000u);
        my[j] = ((u64)u << 32) | (u32)k;
        keys[k] = my[j];
    }
    __syncthreads();

    // rank = #{keys < mine}; unique (idx in low bits) -> direct scatter
    int rank0 = 0, rank1 = 0, rank2 = 0, rank3 = 0;
    #pragma unroll 8
    for (int k = 0; k < K; ++k) {
        u64 kv = keys[k];                 // uniform addr -> broadcast, free
        rank0 += (kv < my[0]) ? 1 : 0;
        rank1 += (kv < my[1]) ? 1 : 0;
        rank2 += (kv < my[2]) ? 1 : 0;
        rank3 += (kv < my[3]) ? 1 : 0;
    }
    skeys[rank0] = my[0];
    skeys[rank1] = my[1];
    skeys[rank2] = my[2];
    skeys[rank3] = my[3];
    __syncthreads();

    // run heads + outputs (identical semantics to verified paths)
    #pragma unroll
    for (int j = 0; j < 4; ++j) {
        int p = j * 256 + t;
        u64 kp = skeys[p];
        u32 vb = (u32)(kp >> 32);
        int p0 = p;
        while (p0 > 0 && (u32)(skeys[p0 - 1] >> 32) == vb) --p0;   // rare (ties)
        int head = (int)(skeys[p0] & 1023u);
        u32 u = (vb & 0x80000000u) ? (vb & 0x7FFFFFFFu) : ~vb;     // unmap
        float v = __uint_as_float(u);
        sval[dcol * K + p] = v;
        shead[dcol * K + p] = (u16)head;
        if (p == 0)     { ext[dcol]     = v; ((int*)ext)[2 * D + dcol] = head; }
        if (p == K - 1) { ext[D + dcol] = v; ((int*)ext)[3 * D + dcol] = head; }
    }
}

// ---------------------------------------------------------------------------
// Kernel A: argmin search with the column LDS-resident (verified round 6).
// Block = (column, 1024-row chunk); 4 independent search chains per thread.
// ---------------------------------------------------------------------------
__global__ __launch_bounds__(256) void search_kernel(
    const float* __restrict__ x, const float* __restrict__ sval,
    const u16* __restrict__ shead, u16* __restrict__ iminT)
{
    __shared__ float svs[K];   // 4 KB sorted column values
    __shared__ u16 shs[K];     // 2 KB run-head indices

    const int col = blockIdx.x & (D - 1);
    const int chunk = blockIdx.x >> 7;
    const int t = threadIdx.x;

    ((float4*)svs)[t] = ((const float4*)(sval + col * K))[t];
    ((uint2*)shs)[t]  = ((const uint2*)(shead + col * K))[t];
    __syncthreads();

    const int b0 = chunk * 1024;
    float xq[4];
    #pragma unroll
    for (int j = 0; j < 4; ++j)
        xq[j] = x[(size_t)(b0 + j * 256 + t) * D + col];   // per-lane gather, once

    // branchless binary search in LDS: pos = last index with sval <= x
    int pos[4];
    #pragma unroll
    for (int r = 0; r < 4; ++r) pos[r] = -1;
    #pragma unroll
    for (int s = K; s >= 1; s >>= 1) {
        #pragma unroll
        for (int r = 0; r < 4; ++r) {
            int cand = pos[r] + s;
            int cc = cand > K - 1 ? K - 1 : cand;
            float v = svs[cc];
            if (cand <= K - 1 && v <= xq[r]) pos[r] = cand;
        }
    }
    #pragma unroll
    for (int r = 0; r < 4; ++r) {
        int p1 = pos[r], p2 = pos[r] + 1;
        int c1 = p1 < 0 ? 0 : p1;
        int c2 = p2 > K - 1 ? K - 1 : p2;
        float v1 = svs[c1], v2 = svs[c2];
        int h1 = shs[c1], h2 = shs[c2];
        float d1 = xq[r] - v1, d2 = xq[r] - v2;
        float s1 = d1 * d1, s2 = d2 * d2;
        if (p1 < 0) s1 = 3.4e38f;
        if (p2 > K - 1) s2 = 3.4e38f;
        int idx;
        if (s1 < s2) idx = h1;
        else if (s2 < s1) idx = h2;
        else idx = h1 < h2 ? h1 : h2;       // sq tie -> smaller original index
        iminT[(size_t)col * NB + b0 + r * 256 + t] = (u16)idx;   // coalesced
    }
}

// ---------------------------------------------------------------------------
// Kernel B: mode (byte-packed LDS counts) + extremes argmax + triplet loss
// (verified round 6).
// ---------------------------------------------------------------------------
__global__ __launch_bounds__(256) void mode_loss_kernel(
    const float* __restrict__ x, const float* __restrict__ cen,
    const u16* __restrict__ iminT, const float* __restrict__ ext,
    float* __restrict__ out)
{
    __shared__ float xs[BB * D];                // 4 KB
    __shared__ u32 cntA[BB * K / 4];            // 8 KB byte-packed (idx_min)
    __shared__ u32 cntB[BB * K / 4];            // 8 KB byte-packed (idx_max)
    __shared__ int modes[2 * BB];

    const int t = threadIdx.x;
    const int b0 = blockIdx.x * BB;

    ((float4*)xs)[t] = ((const float4*)(x + (size_t)b0 * D))[t];
    {
        uint4 z = make_uint4(0u, 0u, 0u, 0u);
        uint4* a4 = (uint4*)cntA;
        uint4* b4 = (uint4*)cntB;
        #pragma unroll
        for (int j = 0; j < 2; ++j) { a4[t + 256 * j] = z; b4[t + 256 * j] = z; }
    }
    __syncthreads();

    // idx_min counts from iminT: thread t covers dim dd, rows half*4..half*4+3
    {
        const int dd = t >> 1, half = t & 1;
        uint2 w = *(const uint2*)(iminT + (size_t)dd * NB + b0 + half * 4);
        int i0 = (int)(w.x & 0xFFFFu), i1 = (int)(w.x >> 16);
        int i2 = (int)(w.y & 0xFFFFu), i3 = (int)(w.y >> 16);
        const int rr = half * 4;
        atomicAdd(&cntA[((rr + 0) << 8) + (i0 >> 2)], 1u << ((i0 & 3) * 8));
        atomicAdd(&cntA[((rr + 1) << 8) + (i1 >> 2)], 1u << ((i1 & 3) * 8));
        atomicAdd(&cntA[((rr + 2) << 8) + (i2 >> 2)], 1u << ((i2 & 3) * 8));
        atomicAdd(&cntA[((rr + 3) << 8) + (i3 >> 2)], 1u << ((i3 & 3) * 8));
    }

    // idx_max from column extremes (reference rounding), direct count-atomic
    const int d = t & (D - 1);
    const int g = t >> 7;
    {
        float cminv = ext[d], cmaxv = ext[D + d];
        int cmini = ((const int*)ext)[2 * D + d];
        int cmaxi = ((const int*)ext)[3 * D + d];
        #pragma unroll
        for (int r = 0; r < 4; ++r) {
            float xv = xs[(g * 4 + r) * D + d];
            float d1 = xv - cminv;
            float d2 = xv - cmaxv;
            float s1 = d1 * d1, s2 = d2 * d2;
            int idx;
            if (s1 > s2) idx = cmini;
            else if (s2 > s1) idx = cmaxi;
            else idx = (cmini < cmaxi) ? cmini : cmaxi;
            const int rr = g * 4 + r;
            atomicAdd(&cntB[(rr << 8) + (idx >> 2)], 1u << ((idx & 3) * 8));
        }
    }
    __syncthreads();

    // mode scan: 32 lanes per row, 8 packed words each, both buffers at once
    const int row = t >> 5;
    const int lane = t & 31;
    {
        u32 bkeyA = 0u, bkeyB = 0u;
        #pragma unroll
        for (int j = 0; j < 8; ++j) {
            const int w = j * 32 + lane;
            u32 wA = cntA[(row << 8) + w];
            u32 wB = cntB[(row << 8) + w];
            #pragma unroll
            for (int sub = 0; sub < 4; ++sub) {
                const u32 idx = (u32)(w * 4 + sub);
                u32 cA = (wA >> (sub * 8)) & 0xFFu;
                u32 cB = (wB >> (sub * 8)) & 0xFFu;
                u32 kA = (cA << 10) | (1023u - idx);
                u32 kB = (cB << 10) | (1023u - idx);
                bkeyA = kA > bkeyA ? kA : bkeyA;
                bkeyB = kB > bkeyB ? kB : bkeyB;
            }
        }
        #pragma unroll
        for (int m = 16; m >= 1; m >>= 1) {
            u32 oA = __shfl_xor(bkeyA, m);
            u32 oB = __shfl_xor(bkeyB, m);
            bkeyA = oA > bkeyA ? oA : bkeyA;
            bkeyB = oB > bkeyB ? oB : bkeyB;
        }
        if (lane == 0) {
            modes[row]      = 1023 - (int)(bkeyA & 1023u);
            modes[BB + row] = 1023 - (int)(bkeyB & 1023u);
        }
    }
    __syncthreads();

    // triplet distances: 32 lanes per row, 4 dims each
    {
        int pm = modes[row];
        int nm = modes[BB + row];
        const float* pr = cen + (size_t)pm * D;
        const float* nr = cen + (size_t)nm * D;
        float a1 = 0.f, a2 = 0.f, a3 = 0.f;
        #pragma unroll
        for (int j = 0; j < 4; ++j) {
            int dd = j * 32 + lane;
            float xv = xs[row * D + dd];
            float pv = pr[dd], nv = nr[dd];
            float e1 = xv - pv + FEPS;
            float e2 = xv - nv + FEPS;
            float e3 = pv - nv + FEPS;
            a1 += e1 * e1; a2 += e2 * e2; a3 += e3 * e3;
        }
        #pragma unroll
        for (int m = 16; m >= 1; m >>= 1) {
            a1 += __shfl_xor(a1, m);
            a2 += __shfl_xor(a2, m);
            a3 += __shfl_xor(a3, m);
        }
        if (lane == 0) {
            float dp = sqrtf(a1);
            float dneg = fminf(sqrtf(a2), sqrtf(a3));
            float term = dp - dneg + 1.0f;
            if (term > 0.f) atomicAdd(out, term * (1.0f / NB));
        }
    }
}

// ===========================================================================
// Fallback path (verified round-1 kernels) for small ws_size
// ===========================================================================
__global__ __launch_bounds__(256) void col_extremes_kernel(
    const float* __restrict__ cen, float* __restrict__ ws)
{
    __shared__ float mv[256]; __shared__ int mi[256];
    __shared__ float Mv[256]; __shared__ int Mi[256];
    const int dcol = blockIdx.x;
    const int t = threadIdx.x;

    float lminv = 3.4e38f; int lmini = 0;
    float lmaxv = -3.4e38f; int lmaxi = 0;
    #pragma unroll
    for (int j = 0; j < 4; ++j) {
        int k = t * 4 + j;
        float v = cen[k * D + dcol];
        if (v < lminv) { lminv = v; lmini = k; }
        if (v > lmaxv) { lmaxv = v; lmaxi = k; }
    }
    mv[t] = lminv; mi[t] = lmini; Mv[t] = lmaxv; Mi[t] = lmaxi;
    __syncthreads();
    for (int s = 128; s > 0; s >>= 1) {
        if (t < s) {
            float ov = mv[t + s]; int oi = mi[t + s];
            if (ov < mv[t] || (ov == mv[t] && oi < mi[t])) { mv[t] = ov; mi[t] = oi; }
            float Ov = Mv[t + s]; int Oi = Mi[t + s];
            if (Ov > Mv[t] || (Ov == Mv[t] && Oi < Mi[t])) { Mv[t] = Ov; Mi[t] = Oi; }
        }
        __syncthreads();
    }
    if (t == 0) {
        ws[dcol]     = mv[0];
        ws[D + dcol] = Mv[0];
        ((int*)ws)[2 * D + dcol] = mi[0];
        ((int*)ws)[3 * D + dcol] = Mi[0];
    }
}

__global__ __launch_bounds__(256) void cluster_triplet_kernel(
    const float* __restrict__ x, const float* __restrict__ cen,
    const float* __restrict__ ws, float* __restrict__ out)
{
    __shared__ float ctile[TK * D];
    __shared__ float xs[BB * D];
    __shared__ u16 imin[BB * D];
    __shared__ u16 imax[BB * D];
    __shared__ int modes[2 * BB];

    const int t = threadIdx.x;
    const int b0 = blockIdx.x * BB;

    ((float4*)xs)[t] = ((const float4*)(x + (size_t)b0 * D))[t];
    __syncthreads();

    const int d = t & (D - 1);
    const int g = t >> 7;

    float xr[4];
    #pragma unroll
    for (int r = 0; r < 4; ++r) xr[r] = xs[(g * 4 + r) * D + d];

    float best[4]; int bidx[4];
    #pragma unroll
    for (int r = 0; r < 4; ++r) { best[r] = 3.4e38f; bidx[r] = 0; }

    for (int kt = 0; kt < K / TK; ++kt) {
        __syncthreads();
        {
            const float4* src = (const float4*)(cen + (size_t)kt * TK * D);
            float4* dst = (float4*)ctile;
            #pragma unroll
            for (int j = 0; j < 8; ++j) dst[t + 256 * j] = src[t + 256 * j];
        }
        __syncthreads();
        #pragma unroll 8
        for (int kk = 0; kk < TK; ++kk) {
            float cv = ctile[kk * D + d];
            int kg = kt * TK + kk;
            #pragma unroll
            for (int r = 0; r < 4; ++r) {
                float ad = fabsf(xr[r] - cv);
                if (ad < best[r]) { best[r] = ad; bidx[r] = kg; }
            }
        }
    }

    #pragma unroll
    for (int r = 0; r < 4; ++r) imin[(g * 4 + r) * D + d] = (u16)bidx[r];

    {
        float cminv = ws[d], cmaxv = ws[D + d];
        int cmini = ((const int*)ws)[2 * D + d];
        int cmaxi = ((const int*)ws)[3 * D + d];
        #pragma unroll
        for (int r = 0; r < 4; ++r) {
            float d1 = xr[r] - cminv;
            float d2 = xr[r] - cmaxv;
            float s1 = d1 * d1, s2 = d2 * d2;
            int idx;
            if (s1 > s2) idx = cmini;
            else if (s2 > s1) idx = cmaxi;
            else idx = (cmini < cmaxi) ? cmini : cmaxi;
            imax[(g * 4 + r) * D + d] = (u16)idx;
        }
    }
    __syncthreads();

    u32* counts = (u32*)ctile;
    const int row = t >> 5;
    const int lane = t & 31;
    for (int pass = 0; pass < 2; ++pass) {
        {
            uint4* cz = (uint4*)counts;
            uint4 z = make_uint4(0u, 0u, 0u, 0u);
            #pragma unroll
            for (int j = 0; j < 8; ++j) cz[t + 256 * j] = z;
        }
        __syncthreads();
        const u16* src = (pass == 0) ? imin : imax;
        #pragma unroll
        for (int r = 0; r < 4; ++r) {
            int rr = g * 4 + r;
            atomicAdd(&counts[rr * K + (int)src[rr * D + d]], 1u);
        }
        __syncthreads();
        u32 bkey = 0u;
        for (int j = 0; j < 32; ++j) {
            int idx = j * 32 + lane;
            u32 cnt = counts[row * K + idx];
            u32 key = (cnt << 10) | (1023u - (u32)idx);
            bkey = (key > bkey) ? key : bkey;
        }
        #pragma unroll
        for (int m = 16; m >= 1; m >>= 1) {
            u32 o = __shfl_xor(bkey, m);
            bkey = (o > bkey) ? o : bkey;
        }
        if (lane == 0) modes[pass * BB + row] = 1023 - (int)(bkey & 1023u);
        __syncthreads();
    }

    {
        int pm = modes[0 * BB + row];
        int nm = modes[1 * BB + row];
        const float* pr = cen + (size_t)pm * D;
        const float* nr = cen + (size_t)nm * D;
        float a1 = 0.f, a2 = 0.f, a3 = 0.f;
        #pragma unroll
        for (int j = 0; j < 4; ++j) {
            int dd = j * 32 + lane;
            float xv = xs[row * D + dd];
            float pv = pr[dd], nv = nr[dd];
            float e1 = xv - pv + FEPS;
            float e2 = xv - nv + FEPS;
            float e3 = pv - nv + FEPS;
            a1 += e1 * e1; a2 += e2 * e2; a3 += e3 * e3;
        }
        #pragma unroll
        for (int m = 16; m >= 1; m >>= 1) {
            a1 += __shfl_xor(a1, m);
            a2 += __shfl_xor(a2, m);
            a3 += __shfl_xor(a3, m);
        }
        if (lane == 0) {
            float dp = sqrtf(a1);
            float dneg = fminf(sqrtf(a2), sqrtf(a3));
            float term = dp - dneg + 1.0f;
            if (term > 0.f) atomicAdd(out, term * (1.0f / NB));
        }
    }
}

extern "C" void kernel_launch(void* const* d_in, const int* in_sizes, int n_in,
                              void* d_out, int out_size, void* d_ws, size_t ws_size,
                              hipStream_t stream) {
    (void)in_sizes; (void)n_in; (void)out_size;
    const float* x   = (const float*)d_in[0];   // [4096,128] f32
    const float* cen = (const float*)d_in[1];   // [1024,128] f32
    float* out = (float*)d_out;                 // scalar f32

    const size_t need = (size_t)D * K * 4        // sval
                      + (size_t)D * K * 2        // shead
                      + (size_t)D * NB * 2       // iminT
                      + (size_t)4 * D * 4;       // ext
    if (ws_size >= need) {
        float* sval = (float*)d_ws;                                 // 512 KB
        u16* shead  = (u16*)(sval + D * K);                         // 256 KB
        u16* iminT  = shead + D * K;                                // 1 MB
        float* ext  = (float*)(iminT + (size_t)D * NB);             // 2 KB
        prep_columns_kernel<<<D, 256, 0, stream>>>(cen, sval, shead, ext, out);
        search_kernel<<<D * (NB / 1024), 256, 0, stream>>>(x, sval, shead, iminT);
        mode_loss_kernel<<<NB / BB, 256, 0, stream>>>(x, cen, iminT, ext, out);
    } else {
        float* ws = (float*)d_ws;
        hipMemsetAsync(d_out, 0, sizeof(float), stream);
        col_extremes_kernel<<<D, 256, 0, stream>>>(cen, ws);
        cluster_triplet_kernel<<<NB / BB, 256, 0, stream>>>(x, cen, ws, out);
    }
}

// Round 8
// 114.409 us; speedup vs baseline: 9.0575x; 1.0219x over previous
//
#include <hip/hip_runtime.h>
#include <cstdint>

#define D 128
#define K 1024
#define NB 4096
#define BB 8     // rows per block in mode/loss kernel
#define TK 64    // centroid rows per LDS tile (fallback path)
#define FEPS 1e-6f

typedef unsigned long long u64;
typedef unsigned int u32;
typedef unsigned short u16;

// ============================================================================
// ws layout (fast path):
//   iminT: [D][NB] u16  — per-(d,b) argmin centroid index, d-major    (1MB)
//   ext  : [0:128) col min val, [128:256) col max val (f32);
//          as ints [256:384) first idx of min, [384:512) first idx of max (2KB)
// (sval/shead no longer round-trip through global — consumed in-LDS.)
// ============================================================================

// ---------------------------------------------------------------------------
// Fused prep+search kernel. One block (512 thr, 8 waves) per column.
//  Phase 1: rank sort by (value,index). Round 7's version exposed ~120cy LDS
//           latency per key at 1 wave/SIMD (measured ~55us); fix = batched
//           ds_read_b128 loads (8 keys/chunk) + 2 waves/SIMD TLP.
//  Phase 2: unpack sorted keys -> svs/shs in LDS, run heads, extremes.
//  Phase 3: binary-search all 4096 rows of x against the LDS column
//           (4 independent chains/thread, verified round-6 logic), write iminT.
// ---------------------------------------------------------------------------
__global__ __launch_bounds__(512) void prep_search_kernel(
    const float* __restrict__ cen, const float* __restrict__ x,
    u16* __restrict__ iminT, float* __restrict__ ext, float* __restrict__ out)
{
    __shared__ u64 keys[K];    // 8 KB original-order keys
    __shared__ u64 skeys[K];   // 8 KB sorted keys
    __shared__ float svs[K];   // 4 KB sorted values
    __shared__ u16 shs[K];     // 2 KB run-head indices

    const int dcol = blockIdx.x;
    const int t = threadIdx.x;            // 0..511
    if (dcol == 0 && t == 0) out[0] = 0.0f;   // replaces memset dispatch

    // ---- load 2 elems (column gather), monotone map, key=(val<<32)|idx ----
    u64 my0, my1;
    {
        float v0 = cen[t * D + dcol];
        float v1 = cen[(t + 512) * D + dcol];
        u32 u0 = __float_as_uint(v0), u1 = __float_as_uint(v1);
        u0 = (u0 & 0x80000000u) ? ~u0 : (u0 | 0x80000000u);
        u1 = (u1 & 0x80000000u) ? ~u1 : (u1 | 0x80000000u);
        my0 = ((u64)u0 << 32) | (u32)t;
        my1 = ((u64)u1 << 32) | (u32)(t + 512);
        keys[t] = my0;
        keys[t + 512] = my1;
    }
    __syncthreads();

    // ---- rank scan, batched: 8 keys per chunk via 4 x ds_read_b128 ----
    int r0 = 0, r1 = 0;
    #pragma unroll 2
    for (int k0 = 0; k0 < K; k0 += 8) {
        ulonglong2 p0 = *(ulonglong2*)&keys[k0];
        ulonglong2 p1 = *(ulonglong2*)&keys[k0 + 2];
        ulonglong2 p2 = *(ulonglong2*)&keys[k0 + 4];
        ulonglong2 p3 = *(ulonglong2*)&keys[k0 + 6];
        u64 kv[8] = { p0.x, p0.y, p1.x, p1.y, p2.x, p2.y, p3.x, p3.y };
        #pragma unroll
        for (int j = 0; j < 8; ++j) {
            r0 += (kv[j] < my0) ? 1 : 0;
            r1 += (kv[j] < my1) ? 1 : 0;
        }
    }
    skeys[r0] = my0;     // ranks unique (idx in low bits) -> collision-free
    skeys[r1] = my1;
    __syncthreads();

    // ---- unpack + run heads + extremes (verified semantics) ----
    #pragma unroll
    for (int j = 0; j < 2; ++j) {
        int p = j * 512 + t;
        u64 kp = skeys[p];
        u32 vb = (u32)(kp >> 32);
        int p0 = p;
        while (p0 > 0 && (u32)(skeys[p0 - 1] >> 32) == vb) --p0;   // rare (ties)
        int head = (int)(skeys[p0] & 1023u);
        u32 u = (vb & 0x80000000u) ? (vb & 0x7FFFFFFFu) : ~vb;     // unmap
        float v = __uint_as_float(u);
        svs[p] = v;
        shs[p] = (u16)head;
        if (p == 0)     { ext[dcol]     = v; ((int*)ext)[2 * D + dcol] = head; }
        if (p == K - 1) { ext[D + dcol] = v; ((int*)ext)[3 * D + dcol] = head; }
    }
    __syncthreads();

    // ---- search all NB rows against the LDS-resident column ----
    #pragma unroll 1
    for (int ph = 0; ph < 2; ++ph) {
        const int b0 = ph * 2048;
        float xq[4];
        #pragma unroll
        for (int j = 0; j < 4; ++j)
            xq[j] = x[(size_t)(b0 + j * 512 + t) * D + dcol];   // gather, L2-hit

        int pos[4];
        #pragma unroll
        for (int r = 0; r < 4; ++r) pos[r] = -1;
        #pragma unroll
        for (int s = K; s >= 1; s >>= 1) {
            #pragma unroll
            for (int r = 0; r < 4; ++r) {
                int cand = pos[r] + s;
                int cc = cand > K - 1 ? K - 1 : cand;
                float v = svs[cc];
                if (cand <= K - 1 && v <= xq[r]) pos[r] = cand;
            }
        }
        #pragma unroll
        for (int r = 0; r < 4; ++r) {
            int p1 = pos[r], p2 = pos[r] + 1;
            int c1 = p1 < 0 ? 0 : p1;
            int c2 = p2 > K - 1 ? K - 1 : p2;
            float v1 = svs[c1], v2 = svs[c2];
            int h1 = shs[c1], h2 = shs[c2];
            float d1 = xq[r] - v1, d2 = xq[r] - v2;
            float s1 = d1 * d1, s2 = d2 * d2;
            if (p1 < 0) s1 = 3.4e38f;
            if (p2 > K - 1) s2 = 3.4e38f;
            int idx;
            if (s1 < s2) idx = h1;
            else if (s2 < s1) idx = h2;
            else idx = h1 < h2 ? h1 : h2;   // sq tie -> smaller original index
            iminT[(size_t)dcol * NB + b0 + r * 512 + t] = (u16)idx;  // coalesced
        }
    }
}

// ---------------------------------------------------------------------------
// Kernel B: mode (byte-packed LDS counts) + extremes argmax + triplet loss
// (verified rounds 6-7, unchanged).
// ---------------------------------------------------------------------------
__global__ __launch_bounds__(256) void mode_loss_kernel(
    const float* __restrict__ x, const float* __restrict__ cen,
    const u16* __restrict__ iminT, const float* __restrict__ ext,
    float* __restrict__ out)
{
    __shared__ float xs[BB * D];                // 4 KB
    __shared__ u32 cntA[BB * K / 4];            // 8 KB byte-packed (idx_min)
    __shared__ u32 cntB[BB * K / 4];            // 8 KB byte-packed (idx_max)
    __shared__ int modes[2 * BB];

    const int t = threadIdx.x;
    const int b0 = blockIdx.x * BB;

    ((float4*)xs)[t] = ((const float4*)(x + (size_t)b0 * D))[t];
    {
        uint4 z = make_uint4(0u, 0u, 0u, 0u);
        uint4* a4 = (uint4*)cntA;
        uint4* b4 = (uint4*)cntB;
        #pragma unroll
        for (int j = 0; j < 2; ++j) { a4[t + 256 * j] = z; b4[t + 256 * j] = z; }
    }
    __syncthreads();

    // idx_min counts from iminT: thread t covers dim dd, rows half*4..half*4+3
    {
        const int dd = t >> 1, half = t & 1;
        uint2 w = *(const uint2*)(iminT + (size_t)dd * NB + b0 + half * 4);
        int i0 = (int)(w.x & 0xFFFFu), i1 = (int)(w.x >> 16);
        int i2 = (int)(w.y & 0xFFFFu), i3 = (int)(w.y >> 16);
        const int rr = half * 4;
        atomicAdd(&cntA[((rr + 0) << 8) + (i0 >> 2)], 1u << ((i0 & 3) * 8));
        atomicAdd(&cntA[((rr + 1) << 8) + (i1 >> 2)], 1u << ((i1 & 3) * 8));
        atomicAdd(&cntA[((rr + 2) << 8) + (i2 >> 2)], 1u << ((i2 & 3) * 8));
        atomicAdd(&cntA[((rr + 3) << 8) + (i3 >> 2)], 1u << ((i3 & 3) * 8));
    }

    // idx_max from column extremes (reference rounding), direct count-atomic
    const int d = t & (D - 1);
    const int g = t >> 7;
    {
        float cminv = ext[d], cmaxv = ext[D + d];
        int cmini = ((const int*)ext)[2 * D + d];
        int cmaxi = ((const int*)ext)[3 * D + d];
        #pragma unroll
        for (int r = 0; r < 4; ++r) {
            float xv = xs[(g * 4 + r) * D + d];
            float d1 = xv - cminv;
            float d2 = xv - cmaxv;
            float s1 = d1 * d1, s2 = d2 * d2;
            int idx;
            if (s1 > s2) idx = cmini;
            else if (s2 > s1) idx = cmaxi;
            else idx = (cmini < cmaxi) ? cmini : cmaxi;
            const int rr = g * 4 + r;
            atomicAdd(&cntB[(rr << 8) + (idx >> 2)], 1u << ((idx & 3) * 8));
        }
    }
    __syncthreads();

    // mode scan: 32 lanes per row, 8 packed words each, both buffers at once
    const int row = t >> 5;
    const int lane = t & 31;
    {
        u32 bkeyA = 0u, bkeyB = 0u;
        #pragma unroll
        for (int j = 0; j < 8; ++j) {
            const int w = j * 32 + lane;
            u32 wA = cntA[(row << 8) + w];
            u32 wB = cntB[(row << 8) + w];
            #pragma unroll
            for (int sub = 0; sub < 4; ++sub) {
                const u32 idx = (u32)(w * 4 + sub);
                u32 cA = (wA >> (sub * 8)) & 0xFFu;
                u32 cB = (wB >> (sub * 8)) & 0xFFu;
                u32 kA = (cA << 10) | (1023u - idx);
                u32 kB = (cB << 10) | (1023u - idx);
                bkeyA = kA > bkeyA ? kA : bkeyA;
                bkeyB = kB > bkeyB ? kB : bkeyB;
            }
        }
        #pragma unroll
        for (int m = 16; m >= 1; m >>= 1) {
            u32 oA = __shfl_xor(bkeyA, m);
            u32 oB = __shfl_xor(bkeyB, m);
            bkeyA = oA > bkeyA ? oA : bkeyA;
            bkeyB = oB > bkeyB ? oB : bkeyB;
        }
        if (lane == 0) {
            modes[row]      = 1023 - (int)(bkeyA & 1023u);
            modes[BB + row] = 1023 - (int)(bkeyB & 1023u);
        }
    }
    __syncthreads();

    // triplet distances: 32 lanes per row, 4 dims each
    {
        int pm = modes[row];
        int nm = modes[BB + row];
        const float* pr = cen + (size_t)pm * D;
        const float* nr = cen + (size_t)nm * D;
        float a1 = 0.f, a2 = 0.f, a3 = 0.f;
        #pragma unroll
        for (int j = 0; j < 4; ++j) {
            int dd = j * 32 + lane;
            float xv = xs[row * D + dd];
            float pv = pr[dd], nv = nr[dd];
            float e1 = xv - pv + FEPS;
            float e2 = xv - nv + FEPS;
            float e3 = pv - nv + FEPS;
            a1 += e1 * e1; a2 += e2 * e2; a3 += e3 * e3;
        }
        #pragma unroll
        for (int m = 16; m >= 1; m >>= 1) {
            a1 += __shfl_xor(a1, m);
            a2 += __shfl_xor(a2, m);
            a3 += __shfl_xor(a3, m);
        }
        if (lane == 0) {
            float dp = sqrtf(a1);
            float dneg = fminf(sqrtf(a2), sqrtf(a3));
            float term = dp - dneg + 1.0f;
            if (term > 0.f) atomicAdd(out, term * (1.0f / NB));
        }
    }
}

// ===========================================================================
// Fallback path (verified round-1 kernels) for small ws_size
// ===========================================================================
__global__ __launch_bounds__(256) void col_extremes_kernel(
    const float* __restrict__ cen, float* __restrict__ ws)
{
    __shared__ float mv[256]; __shared__ int mi[256];
    __shared__ float Mv[256]; __shared__ int Mi[256];
    const int dcol = blockIdx.x;
    const int t = threadIdx.x;

    float lminv = 3.4e38f; int lmini = 0;
    float lmaxv = -3.4e38f; int lmaxi = 0;
    #pragma unroll
    for (int j = 0; j < 4; ++j) {
        int k = t * 4 + j;
        float v = cen[k * D + dcol];
        if (v < lminv) { lminv = v; lmini = k; }
        if (v > lmaxv) { lmaxv = v; lmaxi = k; }
    }
    mv[t] = lminv; mi[t] = lmini; Mv[t] = lmaxv; Mi[t] = lmaxi;
    __syncthreads();
    for (int s = 128; s > 0; s >>= 1) {
        if (t < s) {
            float ov = mv[t + s]; int oi = mi[t + s];
            if (ov < mv[t] || (ov == mv[t] && oi < mi[t])) { mv[t] = ov; mi[t] = oi; }
            float Ov = Mv[t + s]; int Oi = Mi[t + s];
            if (Ov > Mv[t] || (Ov == Mv[t] && Oi < Mi[t])) { Mv[t] = Ov; Mi[t] = Oi; }
        }
        __syncthreads();
    }
    if (t == 0) {
        ws[dcol]     = mv[0];
        ws[D + dcol] = Mv[0];
        ((int*)ws)[2 * D + dcol] = mi[0];
        ((int*)ws)[3 * D + dcol] = Mi[0];
    }
}

__global__ __launch_bounds__(256) void cluster_triplet_kernel(
    const float* __restrict__ x, const float* __restrict__ cen,
    const float* __restrict__ ws, float* __restrict__ out)
{
    __shared__ float ctile[TK * D];
    __shared__ float xs[BB * D];
    __shared__ u16 imin[BB * D];
    __shared__ u16 imax[BB * D];
    __shared__ int modes[2 * BB];

    const int t = threadIdx.x;
    const int b0 = blockIdx.x * BB;

    ((float4*)xs)[t] = ((const float4*)(x + (size_t)b0 * D))[t];
    __syncthreads();

    const int d = t & (D - 1);
    const int g = t >> 7;

    float xr[4];
    #pragma unroll
    for (int r = 0; r < 4; ++r) xr[r] = xs[(g * 4 + r) * D + d];

    float best[4]; int bidx[4];
    #pragma unroll
    for (int r = 0; r < 4; ++r) { best[r] = 3.4e38f; bidx[r] = 0; }

    for (int kt = 0; kt < K / TK; ++kt) {
        __syncthreads();
        {
            const float4* src = (const float4*)(cen + (size_t)kt * TK * D);
            float4* dst = (float4*)ctile;
            #pragma unroll
            for (int j = 0; j < 8; ++j) dst[t + 256 * j] = src[t + 256 * j];
        }
        __syncthreads();
        #pragma unroll 8
        for (int kk = 0; kk < TK; ++kk) {
            float cv = ctile[kk * D + d];
            int kg = kt * TK + kk;
            #pragma unroll
            for (int r = 0; r < 4; ++r) {
                float ad = fabsf(xr[r] - cv);
                if (ad < best[r]) { best[r] = ad; bidx[r] = kg; }
            }
        }
    }

    #pragma unroll
    for (int r = 0; r < 4; ++r) imin[(g * 4 + r) * D + d] = (u16)bidx[r];

    {
        float cminv = ws[d], cmaxv = ws[D + d];
        int cmini = ((const int*)ws)[2 * D + d];
        int cmaxi = ((const int*)ws)[3 * D + d];
        #pragma unroll
        for (int r = 0; r < 4; ++r) {
            float d1 = xr[r] - cminv;
            float d2 = xr[r] - cmaxv;
            float s1 = d1 * d1, s2 = d2 * d2;
            int idx;
            if (s1 > s2) idx = cmini;
            else if (s2 > s1) idx = cmaxi;
            else idx = (cmini < cmaxi) ? cmini : cmaxi;
            imax[(g * 4 + r) * D + d] = (u16)idx;
        }
    }
    __syncthreads();

    u32* counts = (u32*)ctile;
    const int row = t >> 5;
    const int lane = t & 31;
    for (int pass = 0; pass < 2; ++pass) {
        {
            uint4* cz = (uint4*)counts;
            uint4 z = make_uint4(0u, 0u, 0u, 0u);
            #pragma unroll
            for (int j = 0; j < 8; ++j) cz[t + 256 * j] = z;
        }
        __syncthreads();
        const u16* src = (pass == 0) ? imin : imax;
        #pragma unroll
        for (int r = 0; r < 4; ++r) {
            int rr = g * 4 + r;
            atomicAdd(&counts[rr * K + (int)src[rr * D + d]], 1u);
        }
        __syncthreads();
        u32 bkey = 0u;
        for (int j = 0; j < 32; ++j) {
            int idx = j * 32 + lane;
            u32 cnt = counts[row * K + idx];
            u32 key = (cnt << 10) | (1023u - (u32)idx);
            bkey = (key > bkey) ? key : bkey;
        }
        #pragma unroll
        for (int m = 16; m >= 1; m >>= 1) {
            u32 o = __shfl_xor(bkey, m);
            bkey = (o > bkey) ? o : bkey;
        }
        if (lane == 0) modes[pass * BB + row] = 1023 - (int)(bkey & 1023u);
        __syncthreads();
    }

    {
        int pm = modes[0 * BB + row];
        int nm = modes[1 * BB + row];
        const float* pr = cen + (size_t)pm * D;
        const float* nr = cen + (size_t)nm * D;
        float a1 = 0.f, a2 = 0.f, a3 = 0.f;
        #pragma unroll
        for (int j = 0; j < 4; ++j) {
            int dd = j * 32 + lane;
            float xv = xs[row * D + dd];
            float pv = pr[dd], nv = nr[dd];
            float e1 = xv - pv + FEPS;
            float e2 = xv - nv + FEPS;
            float e3 = pv - nv + FEPS;
            a1 += e1 * e1; a2 += e2 * e2; a3 += e3 * e3;
        }
        #pragma unroll
        for (int m = 16; m >= 1; m >>= 1) {
            a1 += __shfl_xor(a1, m);
            a2 += __shfl_xor(a2, m);
            a3 += __shfl_xor(a3, m);
        }
        if (lane == 0) {
            float dp = sqrtf(a1);
            float dneg = fminf(sqrtf(a2), sqrtf(a3));
            float term = dp - dneg + 1.0f;
            if (term > 0.f) atomicAdd(out, term * (1.0f / NB));
        }
    }
}

extern "C" void kernel_launch(void* const* d_in, const int* in_sizes, int n_in,
                              void* d_out, int out_size, void* d_ws, size_t ws_size,
                              hipStream_t stream) {
    (void)in_sizes; (void)n_in; (void)out_size;
    const float* x   = (const float*)d_in[0];   // [4096,128] f32
    const float* cen = (const float*)d_in[1];   // [1024,128] f32
    float* out = (float*)d_out;                 // scalar f32

    const size_t need = (size_t)D * NB * 2       // iminT
                      + (size_t)4 * D * 4;       // ext
    if (ws_size >= need) {
        u16* iminT  = (u16*)d_ws;                                   // 1 MB
        float* ext  = (float*)(iminT + (size_t)D * NB);             // 2 KB
        prep_search_kernel<<<D, 512, 0, stream>>>(cen, x, iminT, ext, out);
        mode_loss_kernel<<<NB / BB, 256, 0, stream>>>(x, cen, iminT, ext, out);
    } else {
        float* ws = (float*)d_ws;
        hipMemsetAsync(d_out, 0, sizeof(float), stream);
        col_extremes_kernel<<<D, 256, 0, stream>>>(cen, ws);
        cluster_triplet_kernel<<<NB / BB, 256, 0, stream>>>(x, cen, ws, out);
    }
}

// Round 9
// 95.569 us; speedup vs baseline: 10.8431x; 1.1971x over previous
//
#include <hip/hip_runtime.h>
#include <cstdint>

#define D 128
#define K 1024
#define NB 4096
#define BB 8     // rows per block in mode/loss kernel
#define TK 64    // centroid rows per LDS tile (fallback path)
#define FEPS 1e-6f

typedef unsigned long long u64;
typedef unsigned int u32;
typedef unsigned short u16;

// ============================================================================
// ws layout (fast path):
//   iminT: [D][NB] u16  — per-(d,b) argmin centroid index, d-major    (1MB)
//   ext  : [0:128) col min val, [128:256) col max val (f32);
//          as ints [256:384) first idx of min, [384:512) first idx of max (2KB)
// ============================================================================

// Monotone non-decreasing value->bin map. Same formula/constants for keys and
// queries => cross-properties hold: keys in bins < bin(x) are < x, keys in
// bins > bin(x) are > x, so the global lower_bound lies inside bin(x)'s range.
__device__ __forceinline__ int vbin(float v, float vmin, float scale) {
    float fb = (v - vmin) * scale;
    fb = fminf(fmaxf(fb, 0.0f), 255.0f);
    return (int)fb;
}

// ---------------------------------------------------------------------------
// Fused prep+search, one block (512 thr) per column.
//  Phase A: bin-rank sort by (value,index) — O(K*avgbin) not O(K^2).
//           (Round 7/8's all-pairs rank scan was LDS-broadcast-bound: 4MB LDS
//           traffic/block. Bins cut it ~60x. Value-space bins + parallel
//           in-bin rank => no round-6-style serial degeneration; output order
//           is bit-identical to the verified rank sort.)
//  Phase B: search all 4096 rows; lower_bound restricted to bin(x)'s slice
//           (~2-3 LDS probes vs 11 levels). Tie logic verbatim-verified.
// ---------------------------------------------------------------------------
__global__ __launch_bounds__(512) void prep_search_kernel(
    const float* __restrict__ cen, const float* __restrict__ x,
    u16* __restrict__ iminT, float* __restrict__ ext, float* __restrict__ out)
{
    __shared__ u64 bkeys[K];      // 8 KB keys scattered by bin
    __shared__ u64 skeys[K];      // 8 KB fully sorted keys
    __shared__ float svs[K];      // 4 KB sorted values
    __shared__ u16 shs[K];        // 2 KB run-head indices
    __shared__ u32 binstart[257]; // exclusive bin starts + sentinel
    __shared__ u32 pfx[256];
    __shared__ u32 cursor[256];
    __shared__ float redmn[8], redmx[8];

    const int dcol = blockIdx.x;
    const int t = threadIdx.x;            // 0..511
    const int wave = t >> 6, lane = t & 63;
    if (dcol == 0 && t == 0) out[0] = 0.0f;   // replaces memset dispatch

    // ---- load 2 elems (column gather) ----
    const float v0 = cen[t * D + dcol];
    const float v1 = cen[(t + 512) * D + dcol];

    // ---- block min/max (float) for bin scale ----
    float mn = fminf(v0, v1), mx = fmaxf(v0, v1);
    #pragma unroll
    for (int s = 32; s >= 1; s >>= 1) {
        mn = fminf(mn, __shfl_xor(mn, s, 64));
        mx = fmaxf(mx, __shfl_xor(mx, s, 64));
    }
    if (lane == 0) { redmn[wave] = mn; redmx[wave] = mx; }
    if (t < 257) binstart[t] = 0u;      // reused as histogram first
    if (t < 256) cursor[t] = 0u;
    __syncthreads();

    float vmin = redmn[0], vmax = redmx[0];
    #pragma unroll
    for (int w = 1; w < 8; ++w) {
        vmin = fminf(vmin, redmn[w]);
        vmax = fmaxf(vmax, redmx[w]);
    }
    const float range = vmax - vmin;
    const float scale = (range > 0.0f) ? (255.0f / range) : 0.0f;

    // ---- keys + histogram ----
    u32 u0 = __float_as_uint(v0), u1 = __float_as_uint(v1);
    u0 = (u0 & 0x80000000u) ? ~u0 : (u0 | 0x80000000u);   // monotone bit map
    u1 = (u1 & 0x80000000u) ? ~u1 : (u1 | 0x80000000u);
    const u64 k0 = ((u64)u0 << 32) | (u32)t;
    const u64 k1 = ((u64)u1 << 32) | (u32)(t + 512);
    const int b0v = vbin(v0, vmin, scale);
    const int b1v = vbin(v1, vmin, scale);
    atomicAdd(&binstart[b0v], 1u);
    atomicAdd(&binstart[b1v], 1u);
    __syncthreads();

    // ---- exclusive prefix over 256 bins (Hillis-Steele on inclusive) ----
    u32 myh = 0u;
    if (t < 256) { myh = binstart[t]; pfx[t] = myh; }
    __syncthreads();
    #pragma unroll
    for (int s = 1; s < 256; s <<= 1) {
        u32 add = 0u;
        if (t < 256 && t >= s) add = pfx[t - s];
        __syncthreads();
        if (t < 256) pfx[t] += add;
        __syncthreads();
    }
    if (t < 256) {
        u32 st = pfx[t] - myh;            // exclusive start
        binstart[t] = st;                 // overwrite histogram with starts
        cursor[t] = st;
    }
    if (t == 0) binstart[256] = K;
    __syncthreads();

    // ---- scatter by bin (within-bin order arbitrary) ----
    { u32 s0 = atomicAdd(&cursor[b0v], 1u); bkeys[s0] = k0; }
    { u32 s1 = atomicAdd(&cursor[b1v], 1u); bkeys[s1] = k1; }
    __syncthreads();

    // ---- in-bin rank (parallel over elements; avg ~4 compares) ----
    {
        int lo = (int)binstart[b0v], hi = (int)binstart[b0v + 1];
        int r = lo;
        for (int p = lo; p < hi; ++p) r += (bkeys[p] < k0) ? 1 : 0;
        skeys[r] = k0;                    // ranks unique (idx in low bits)
    }
    {
        int lo = (int)binstart[b1v], hi = (int)binstart[b1v + 1];
        int r = lo;
        for (int p = lo; p < hi; ++p) r += (bkeys[p] < k1) ? 1 : 0;
        skeys[r] = k1;
    }
    __syncthreads();

    // ---- unpack + run heads + extremes (verified semantics) ----
    #pragma unroll
    for (int j = 0; j < 2; ++j) {
        int p = j * 512 + t;
        u64 kp = skeys[p];
        u32 vb = (u32)(kp >> 32);
        int p0 = p;
        while (p0 > 0 && (u32)(skeys[p0 - 1] >> 32) == vb) --p0;   // rare (ties)
        int head = (int)(skeys[p0] & 1023u);
        u32 u = (vb & 0x80000000u) ? (vb & 0x7FFFFFFFu) : ~vb;     // unmap
        float v = __uint_as_float(u);
        svs[p] = v;
        shs[p] = (u16)head;
        if (p == 0)     { ext[dcol]     = v; ((int*)ext)[2 * D + dcol] = head; }
        if (p == K - 1) { ext[D + dcol] = v; ((int*)ext)[3 * D + dcol] = head; }
    }
    __syncthreads();

    // ---- Phase B: search all NB rows, lower_bound within bin(x)'s slice ----
    #pragma unroll 1
    for (int ph = 0; ph < 2; ++ph) {
        const int b0 = ph * 2048;
        float xq[4];
        #pragma unroll
        for (int j = 0; j < 4; ++j)
            xq[j] = x[(size_t)(b0 + j * 512 + t) * D + dcol];   // gather, L2-hit

        #pragma unroll
        for (int r = 0; r < 4; ++r) {
            const float xv = xq[r];
            const int bx = vbin(xv, vmin, scale);
            int lo = (int)binstart[bx], hi = (int)binstart[bx + 1];
            // first position with svs[pos] > xv (== global lower_bound; proof:
            // keys in bins < bx are < xv, keys in bins > bx are > xv)
            while (lo < hi) {
                int mid = (lo + hi) >> 1;
                if (svs[mid] <= xv) lo = mid + 1; else hi = mid;
            }
            const int p1 = lo - 1, p2 = lo;
            const int c1 = p1 < 0 ? 0 : p1;
            const int c2 = p2 > K - 1 ? K - 1 : p2;
            float vv1 = svs[c1], vv2 = svs[c2];
            int h1 = shs[c1], h2 = shs[c2];
            float d1 = xv - vv1, d2 = xv - vv2;
            float s1 = d1 * d1, s2 = d2 * d2;
            if (p1 < 0) s1 = 3.4e38f;
            if (p2 > K - 1) s2 = 3.4e38f;
            int idx;
            if (s1 < s2) idx = h1;
            else if (s2 < s1) idx = h2;
            else idx = h1 < h2 ? h1 : h2;   // sq tie -> smaller original index
            iminT[(size_t)dcol * NB + b0 + r * 512 + t] = (u16)idx;  // coalesced
        }
    }
}

// ---------------------------------------------------------------------------
// Kernel B: mode (byte-packed LDS counts) + extremes argmax + triplet loss
// (verified rounds 6-8, unchanged).
// ---------------------------------------------------------------------------
__global__ __launch_bounds__(256) void mode_loss_kernel(
    const float* __restrict__ x, const float* __restrict__ cen,
    const u16* __restrict__ iminT, const float* __restrict__ ext,
    float* __restrict__ out)
{
    __shared__ float xs[BB * D];                // 4 KB
    __shared__ u32 cntA[BB * K / 4];            // 8 KB byte-packed (idx_min)
    __shared__ u32 cntB[BB * K / 4];            // 8 KB byte-packed (idx_max)
    __shared__ int modes[2 * BB];

    const int t = threadIdx.x;
    const int b0 = blockIdx.x * BB;

    ((float4*)xs)[t] = ((const float4*)(x + (size_t)b0 * D))[t];
    {
        uint4 z = make_uint4(0u, 0u, 0u, 0u);
        uint4* a4 = (uint4*)cntA;
        uint4* b4 = (uint4*)cntB;
        #pragma unroll
        for (int j = 0; j < 2; ++j) { a4[t + 256 * j] = z; b4[t + 256 * j] = z; }
    }
    __syncthreads();

    // idx_min counts from iminT: thread t covers dim dd, rows half*4..half*4+3
    {
        const int dd = t >> 1, half = t & 1;
        uint2 w = *(const uint2*)(iminT + (size_t)dd * NB + b0 + half * 4);
        int i0 = (int)(w.x & 0xFFFFu), i1 = (int)(w.x >> 16);
        int i2 = (int)(w.y & 0xFFFFu), i3 = (int)(w.y >> 16);
        const int rr = half * 4;
        atomicAdd(&cntA[((rr + 0) << 8) + (i0 >> 2)], 1u << ((i0 & 3) * 8));
        atomicAdd(&cntA[((rr + 1) << 8) + (i1 >> 2)], 1u << ((i1 & 3) * 8));
        atomicAdd(&cntA[((rr + 2) << 8) + (i2 >> 2)], 1u << ((i2 & 3) * 8));
        atomicAdd(&cntA[((rr + 3) << 8) + (i3 >> 2)], 1u << ((i3 & 3) * 8));
    }

    // idx_max from column extremes (reference rounding), direct count-atomic
    const int d = t & (D - 1);
    const int g = t >> 7;
    {
        float cminv = ext[d], cmaxv = ext[D + d];
        int cmini = ((const int*)ext)[2 * D + d];
        int cmaxi = ((const int*)ext)[3 * D + d];
        #pragma unroll
        for (int r = 0; r < 4; ++r) {
            float xv = xs[(g * 4 + r) * D + d];
            float d1 = xv - cminv;
            float d2 = xv - cmaxv;
            float s1 = d1 * d1, s2 = d2 * d2;
            int idx;
            if (s1 > s2) idx = cmini;
            else if (s2 > s1) idx = cmaxi;
            else idx = (cmini < cmaxi) ? cmini : cmaxi;
            const int rr = g * 4 + r;
            atomicAdd(&cntB[(rr << 8) + (idx >> 2)], 1u << ((idx & 3) * 8));
        }
    }
    __syncthreads();

    // mode scan: 32 lanes per row, 8 packed words each, both buffers at once
    const int row = t >> 5;
    const int lane = t & 31;
    {
        u32 bkeyA = 0u, bkeyB = 0u;
        #pragma unroll
        for (int j = 0; j < 8; ++j) {
            const int w = j * 32 + lane;
            u32 wA = cntA[(row << 8) + w];
            u32 wB = cntB[(row << 8) + w];
            #pragma unroll
            for (int sub = 0; sub < 4; ++sub) {
                const u32 idx = (u32)(w * 4 + sub);
                u32 cA = (wA >> (sub * 8)) & 0xFFu;
                u32 cB = (wB >> (sub * 8)) & 0xFFu;
                u32 kA = (cA << 10) | (1023u - idx);
                u32 kB = (cB << 10) | (1023u - idx);
                bkeyA = kA > bkeyA ? kA : bkeyA;
                bkeyB = kB > bkeyB ? kB : bkeyB;
            }
        }
        #pragma unroll
        for (int m = 16; m >= 1; m >>= 1) {
            u32 oA = __shfl_xor(bkeyA, m);
            u32 oB = __shfl_xor(bkeyB, m);
            bkeyA = oA > bkeyA ? oA : bkeyA;
            bkeyB = oB > bkeyB ? oB : bkeyB;
        }
        if (lane == 0) {
            modes[row]      = 1023 - (int)(bkeyA & 1023u);
            modes[BB + row] = 1023 - (int)(bkeyB & 1023u);
        }
    }
    __syncthreads();

    // triplet distances: 32 lanes per row, 4 dims each
    {
        int pm = modes[row];
        int nm = modes[BB + row];
        const float* pr = cen + (size_t)pm * D;
        const float* nr = cen + (size_t)nm * D;
        float a1 = 0.f, a2 = 0.f, a3 = 0.f;
        #pragma unroll
        for (int j = 0; j < 4; ++j) {
            int dd = j * 32 + lane;
            float xv = xs[row * D + dd];
            float pv = pr[dd], nv = nr[dd];
            float e1 = xv - pv + FEPS;
            float e2 = xv - nv + FEPS;
            float e3 = pv - nv + FEPS;
            a1 += e1 * e1; a2 += e2 * e2; a3 += e3 * e3;
        }
        #pragma unroll
        for (int m = 16; m >= 1; m >>= 1) {
            a1 += __shfl_xor(a1, m);
            a2 += __shfl_xor(a2, m);
            a3 += __shfl_xor(a3, m);
        }
        if (lane == 0) {
            float dp = sqrtf(a1);
            float dneg = fminf(sqrtf(a2), sqrtf(a3));
            float term = dp - dneg + 1.0f;
            if (term > 0.f) atomicAdd(out, term * (1.0f / NB));
        }
    }
}

// ===========================================================================
// Fallback path (verified round-1 kernels) for small ws_size
// ===========================================================================
__global__ __launch_bounds__(256) void col_extremes_kernel(
    const float* __restrict__ cen, float* __restrict__ ws)
{
    __shared__ float mv[256]; __shared__ int mi[256];
    __shared__ float Mv[256]; __shared__ int Mi[256];
    const int dcol = blockIdx.x;
    const int t = threadIdx.x;

    float lminv = 3.4e38f; int lmini = 0;
    float lmaxv = -3.4e38f; int lmaxi = 0;
    #pragma unroll
    for (int j = 0; j < 4; ++j) {
        int k = t * 4 + j;
        float v = cen[k * D + dcol];
        if (v < lminv) { lminv = v; lmini = k; }
        if (v > lmaxv) { lmaxv = v; lmaxi = k; }
    }
    mv[t] = lminv; mi[t] = lmini; Mv[t] = lmaxv; Mi[t] = lmaxi;
    __syncthreads();
    for (int s = 128; s > 0; s >>= 1) {
        if (t < s) {
            float ov = mv[t + s]; int oi = mi[t + s];
            if (ov < mv[t] || (ov == mv[t] && oi < mi[t])) { mv[t] = ov; mi[t] = oi; }
            float Ov = Mv[t + s]; int Oi = Mi[t + s];
            if (Ov > Mv[t] || (Ov == Mv[t] && Oi < Mi[t])) { Mv[t] = Ov; Mi[t] = Oi; }
        }
        __syncthreads();
    }
    if (t == 0) {
        ws[dcol]     = mv[0];
        ws[D + dcol] = Mv[0];
        ((int*)ws)[2 * D + dcol] = mi[0];
        ((int*)ws)[3 * D + dcol] = Mi[0];
    }
}

__global__ __launch_bounds__(256) void cluster_triplet_kernel(
    const float* __restrict__ x, const float* __restrict__ cen,
    const float* __restrict__ ws, float* __restrict__ out)
{
    __shared__ float ctile[TK * D];
    __shared__ float xs[BB * D];
    __shared__ u16 imin[BB * D];
    __shared__ u16 imax[BB * D];
    __shared__ int modes[2 * BB];

    const int t = threadIdx.x;
    const int b0 = blockIdx.x * BB;

    ((float4*)xs)[t] = ((const float4*)(x + (size_t)b0 * D))[t];
    __syncthreads();

    const int d = t & (D - 1);
    const int g = t >> 7;

    float xr[4];
    #pragma unroll
    for (int r = 0; r < 4; ++r) xr[r] = xs[(g * 4 + r) * D + d];

    float best[4]; int bidx[4];
    #pragma unroll
    for (int r = 0; r < 4; ++r) { best[r] = 3.4e38f; bidx[r] = 0; }

    for (int kt = 0; kt < K / TK; ++kt) {
        __syncthreads();
        {
            const float4* src = (const float4*)(cen + (size_t)kt * TK * D);
            float4* dst = (float4*)ctile;
            #pragma unroll
            for (int j = 0; j < 8; ++j) dst[t + 256 * j] = src[t + 256 * j];
        }
        __syncthreads();
        #pragma unroll 8
        for (int kk = 0; kk < TK; ++kk) {
            float cv = ctile[kk * D + d];
            int kg = kt * TK + kk;
            #pragma unroll
            for (int r = 0; r < 4; ++r) {
                float ad = fabsf(xr[r] - cv);
                if (ad < best[r]) { best[r] = ad; bidx[r] = kg; }
            }
        }
    }

    #pragma unroll
    for (int r = 0; r < 4; ++r) imin[(g * 4 + r) * D + d] = (u16)bidx[r];

    {
        float cminv = ws[d], cmaxv = ws[D + d];
        int cmini = ((const int*)ws)[2 * D + d];
        int cmaxi = ((const int*)ws)[3 * D + d];
        #pragma unroll
        for (int r = 0; r < 4; ++r) {
            float d1 = xr[r] - cminv;
            float d2 = xr[r] - cmaxv;
            float s1 = d1 * d1, s2 = d2 * d2;
            int idx;
            if (s1 > s2) idx = cmini;
            else if (s2 > s1) idx = cmaxi;
            else idx = (cmini < cmaxi) ? cmini : cmaxi;
            imax[(g * 4 + r) * D + d] = (u16)idx;
        }
    }
    __syncthreads();

    u32* counts = (u32*)ctile;
    const int row = t >> 5;
    const int lane = t & 31;
    for (int pass = 0; pass < 2; ++pass) {
        {
            uint4* cz = (uint4*)counts;
            uint4 z = make_uint4(0u, 0u, 0u, 0u);
            #pragma unroll
            for (int j = 0; j < 8; ++j) cz[t + 256 * j] = z;
        }
        __syncthreads();
        const u16* src = (pass == 0) ? imin : imax;
        #pragma unroll
        for (int r = 0; r < 4; ++r) {
            int rr = g * 4 + r;
            atomicAdd(&counts[rr * K + (int)src[rr * D + d]], 1u);
        }
        __syncthreads();
        u32 bkey = 0u;
        for (int j = 0; j < 32; ++j) {
            int idx = j * 32 + lane;
            u32 cnt = counts[row * K + idx];
            u32 key = (cnt << 10) | (1023u - (u32)idx);
            bkey = (key > bkey) ? key : bkey;
        }
        #pragma unroll
        for (int m = 16; m >= 1; m >>= 1) {
            u32 o = __shfl_xor(bkey, m);
            bkey = (o > bkey) ? o : bkey;
        }
        if (lane == 0) modes[pass * BB + row] = 1023 - (int)(bkey & 1023u);
        __syncthreads();
    }

    {
        int pm = modes[0 * BB + row];
        int nm = modes[1 * BB + row];
        const float* pr = cen + (size_t)pm * D;
        const float* nr = cen + (size_t)nm * D;
        float a1 = 0.f, a2 = 0.f, a3 = 0.f;
        #pragma unroll
        for (int j = 0; j < 4; ++j) {
            int dd = j * 32 + lane;
            float xv = xs[row * D + dd];
            float pv = pr[dd], nv = nr[dd];
            float e1 = xv - pv + FEPS;
            float e2 = xv - nv + FEPS;
            float e3 = pv - nv + FEPS;
            a1 += e1 * e1; a2 += e2 * e2; a3 += e3 * e3;
        }
        #pragma unroll
        for (int m = 16; m >= 1; m >>= 1) {
            a1 += __shfl_xor(a1, m);
            a2 += __shfl_xor(a2, m);
            a3 += __shfl_xor(a3, m);
        }
        if (lane == 0) {
            float dp = sqrtf(a1);
            float dneg = fminf(sqrtf(a2), sqrtf(a3));
            float term = dp - dneg + 1.0f;
            if (term > 0.f) atomicAdd(out, term * (1.0f / NB));
        }
    }
}

extern "C" void kernel_launch(void* const* d_in, const int* in_sizes, int n_in,
                              void* d_out, int out_size, void* d_ws, size_t ws_size,
                              hipStream_t stream) {
    (void)in_sizes; (void)n_in; (void)out_size;
    const float* x   = (const float*)d_in[0];   // [4096,128] f32
    const float* cen = (const float*)d_in[1];   // [1024,128] f32
    float* out = (float*)d_out;                 // scalar f32

    const size_t need = (size_t)D * NB * 2       // iminT
                      + (size_t)4 * D * 4;       // ext
    if (ws_size >= need) {
        u16* iminT  = (u16*)d_ws;                                   // 1 MB
        float* ext  = (float*)(iminT + (size_t)D * NB);             // 2 KB
        prep_search_kernel<<<D, 512, 0, stream>>>(cen, x, iminT, ext, out);
        mode_loss_kernel<<<NB / BB, 256, 0, stream>>>(x, cen, iminT, ext, out);
    } else {
        float* ws = (float*)d_ws;
        hipMemsetAsync(d_out, 0, sizeof(float), stream);
        col_extremes_kernel<<<D, 256, 0, stream>>>(cen, ws);
        cluster_triplet_kernel<<<NB / BB, 256, 0, stream>>>(x, cen, ws, out);
    }
}